// Round 14
// baseline (188.427 us; speedup 1.0000x reference)
//
#include <hip/hip_runtime.h>
#include <cstdint>
#include <cfloat>
#include <math.h>

typedef __bf16 bf16_t;
typedef __bf16 bf16x8 __attribute__((ext_vector_type(8)));
typedef __bf16 bf16x4 __attribute__((ext_vector_type(4)));
typedef float  f32x4  __attribute__((ext_vector_type(4)));
typedef unsigned int u32;

#define NEGF (-3.4028234663852886e38f)

static __device__ __forceinline__ f32x4 mfma16(bf16x8 a, bf16x8 b, f32x4 c) {
  return __builtin_amdgcn_mfma_f32_16x16x32_bf16(a, b, c, 0, 0, 0);
}
static __device__ __forceinline__ void gload_lds16(const bf16_t* g, bf16_t* l) {
  __builtin_amdgcn_global_load_lds((const __attribute__((address_space(1))) void*)g,
                                   (__attribute__((address_space(3))) void*)l, 16, 0, 0);
}

// ---------------- fused prep: mask decode + x cast + weight transpose ----------------
__global__ __launch_bounds__(256) void k_prep_all(const float* __restrict__ x,
                                                  const uint8_t* __restrict__ mraw,
                                                  const float* __restrict__ Wq,
                                                  const float* __restrict__ Wk,
                                                  const float* __restrict__ Wv,
                                                  const float* __restrict__ Wo,
                                                  bf16_t* __restrict__ xb,
                                                  bf16_t* __restrict__ WT,
                                                  bf16_t* __restrict__ WoT,
                                                  uint8_t* __restrict__ valid) {
  int bid = blockIdx.x;
  int tid = threadIdx.x;
  if (bid < 8192) {                      // cast x -> bf16
    int i = bid * 256 + tid;
    float4 v = ((const float4*)x)[i];
    bf16x4 o = { (bf16_t)v.x, (bf16_t)v.y, (bf16_t)v.z, (bf16_t)v.w };
    *(bf16x4*)(xb + (size_t)i * 4) = o;
  } else if (bid < 12288) {              // transpose+cast weights
    __shared__ float tile[32][33];
    int zz = bid - 8192;
    int z = zz >> 10, rem = zz & 1023;
    int bx = rem & 31, by = rem >> 5;
    const float* src = (z == 0) ? Wq : (z == 1) ? Wk : (z == 2) ? Wv : Wo;
    bf16_t* dst = (z < 3) ? (WT + (size_t)z * 1024 * 1024) : WoT;
    int x0 = bx * 32, y0 = by * 32;
    int tx = tid & 31, ty = tid >> 5;
    #pragma unroll
    for (int j = 0; j < 32; j += 8)
      tile[ty + j][tx] = src[(size_t)(y0 + ty + j) * 1024 + x0 + tx];
    __syncthreads();
    #pragma unroll
    for (int j = 0; j < 32; j += 8)
      dst[(size_t)(x0 + ty + j) * 1024 + y0 + tx] = (bf16_t)tile[tx][ty + j];
  } else {                               // mask decode (layout auto-detect)
    __shared__ int f1, f3;
    if (tid == 0) { f1 = 0; f3 = 0; }
    __syncthreads();
    int l1 = 0, l3 = 0;
    for (int i = tid; i < 8192; i += 256) {
      uint8_t v = mraw[i];
      if (v) { int r = i & 3; if (r == 1 || r == 2) l1 = 1; if (r == 3) l3 = 1; }
    }
    if (l1) atomicOr(&f1, 1);
    if (l3) atomicOr(&f3, 1);
    __syncthreads();
    int layout = f1 ? 0 : (f3 ? 2 : 1);
    for (int i = tid; i < 8192; i += 256) {
      bool m;
      if (layout == 0)      m = mraw[i] != 0;
      else if (layout == 1) m = ((const int*)mraw)[i] != 0;
      else                  m = ((const float*)mraw)[i] != 0.0f;
      valid[i] = m ? (uint8_t)0 : (uint8_t)1;
    }
  }
}

// ---------------- 8-phase pipelined GEMM (QKV, bf16 out): C = A * Bt^T ----------------
// BM=256 BN=128 BK=64, 512 thr (8 waves 4Mx2N, per-wave 64x64), dbuf LDS 96KB.
// Per K-tile: 4 phases {ds-read quadrant ; stage 1 half-tile of t+1 ; barrier ;
// lgkmcnt(0)+sched_barrier ; setprio(1) 8 MFMA setprio(0) ; barrier}. Drain vmcnt(0)
// only at the tile boundary, on loads issued 1-3 phases earlier (near-cold).
// Race-free: tile t reads slot t&1; t+1 stages slot (t+1)&1 whose last reader (t-1)
// finished before t began. Requires M%256==0, N%128==0, K%64==0, grid=768 (M=8192,N=3072).
__global__ __launch_bounds__(512) void k_gemm8p(const bf16_t* __restrict__ A,
                                                const bf16_t* __restrict__ Bt,
                                                bf16_t* __restrict__ C,
                                                int M, int N, int K) {
  __shared__ __align__(16) uint8_t shmem[98304];   // 2 slots x (A 32KB + B 16KB)
  bf16_t* lds = (bf16_t*)shmem;
  const int NT = K >> 6;
  int id = blockIdx.x;
  int xcd = id & 7, seq = id >> 3;
  int nbg = seq >> 5, inner = seq & 31;            // per-XCD group: 4 mb x 8 nb
  int mb = (xcd << 2) + (inner >> 3);              // A band 2MB + B panel 2MB per group
  int nb = (nbg << 3) + (inner & 7);

  const int tid = threadIdx.x;
  const int lane = tid & 63, wv = tid >> 6;
  const int c = lane & 15, g = lane >> 4;
  const size_t m0 = (size_t)mb * 256, n0 = (size_t)nb * 128;
  const int wm = (wv >> 1) * 64, wn = (wv & 1) * 64;   // 4M x 2N waves

  auto stageA = [&](int t, int half) {             // 128 rows (16KB): 2 loads/thread
    #pragma unroll
    for (int p = 0; p < 2; ++p) {
      int seg = half * 1024 + p * 512 + tid;
      int r = seg >> 3, s = seg & 7;
      int sc = (s ^ (r & 7)) * 8;
      gload_lds16(A + (m0 + r) * (size_t)K + (t << 6) + sc,
                  lds + (t & 1) * 24576 + seg * 8);
    }
  };
  auto stageB = [&](int t) {                       // 128 rows (16KB): 2 loads/thread
    #pragma unroll
    for (int p = 0; p < 2; ++p) {
      int seg = p * 512 + tid;
      int r = seg >> 3, s = seg & 7;
      int sc = (s ^ (r & 7)) * 8;
      gload_lds16(Bt + (n0 + r) * (size_t)K + (t << 6) + sc,
                  lds + (t & 1) * 24576 + 16384 + seg * 8);
    }
  };

  f32x4 zero = {0.f, 0.f, 0.f, 0.f};
  f32x4 acc[4][4];
  #pragma unroll
  for (int m = 0; m < 4; ++m)
    #pragma unroll
    for (int n = 0; n < 4; ++n) acc[m][n] = zero;

  // prologue: stage tile 0 fully, drain, barrier
  stageA(0, 0); stageA(0, 1); stageB(0);
  asm volatile("s_waitcnt vmcnt(0)" ::: "memory");
  __builtin_amdgcn_s_barrier();

  for (int t = 0; t < NT; ++t) {
    const bf16_t* As = lds + (t & 1) * 24576;
    const bf16_t* Bs = As + 16384;
    bool pf = (t + 1) < NT;
    bf16x8 bA[2][2], bB[4][2];                     // m-pair x k | 4 n x k

    // ---- phase 0: read A m{0,1} + B n{0,1}; stage A-half0(t+1); MFMA m01 x n01
    #pragma unroll
    for (int m = 0; m < 2; ++m) {
      int row = wm + m * 16 + c;
      bA[m][0] = *(const bf16x8*)(As + row * 64 + ((g       ^ (row & 7)) * 8));
      bA[m][1] = *(const bf16x8*)(As + row * 64 + (((g + 4) ^ (row & 7)) * 8));
    }
    #pragma unroll
    for (int n = 0; n < 2; ++n) {
      int row = wn + n * 16 + c;
      bB[n][0] = *(const bf16x8*)(Bs + row * 64 + ((g       ^ (row & 7)) * 8));
      bB[n][1] = *(const bf16x8*)(Bs + row * 64 + (((g + 4) ^ (row & 7)) * 8));
    }
    if (pf) stageA(t + 1, 0);
    __builtin_amdgcn_s_barrier();
    asm volatile("s_waitcnt lgkmcnt(0)" ::: "memory");
    __builtin_amdgcn_sched_barrier(0);
    __builtin_amdgcn_s_setprio(1);
    #pragma unroll
    for (int m = 0; m < 2; ++m)
      #pragma unroll
      for (int n = 0; n < 2; ++n) {
        acc[m][n] = mfma16(bA[m][0], bB[n][0], acc[m][n]);
        acc[m][n] = mfma16(bA[m][1], bB[n][1], acc[m][n]);
      }
    __builtin_amdgcn_s_setprio(0);
    __builtin_amdgcn_s_barrier();

    // ---- phase 1: read B n{2,3}; stage A-half1(t+1); MFMA m01 x n23
    #pragma unroll
    for (int n = 2; n < 4; ++n) {
      int row = wn + n * 16 + c;
      bB[n][0] = *(const bf16x8*)(Bs + row * 64 + ((g       ^ (row & 7)) * 8));
      bB[n][1] = *(const bf16x8*)(Bs + row * 64 + (((g + 4) ^ (row & 7)) * 8));
    }
    if (pf) stageA(t + 1, 1);
    __builtin_amdgcn_s_barrier();
    asm volatile("s_waitcnt lgkmcnt(0)" ::: "memory");
    __builtin_amdgcn_sched_barrier(0);
    __builtin_amdgcn_s_setprio(1);
    #pragma unroll
    for (int m = 0; m < 2; ++m)
      #pragma unroll
      for (int n = 2; n < 4; ++n) {
        acc[m][n] = mfma16(bA[m][0], bB[n][0], acc[m][n]);
        acc[m][n] = mfma16(bA[m][1], bB[n][1], acc[m][n]);
      }
    __builtin_amdgcn_s_setprio(0);
    __builtin_amdgcn_s_barrier();

    // ---- phase 2: read A m{2,3}; stage B(t+1); MFMA m23 x n01 (bB n01 held in regs)
    #pragma unroll
    for (int m = 0; m < 2; ++m) {
      int row = wm + (m + 2) * 16 + c;
      bA[m][0] = *(const bf16x8*)(As + row * 64 + ((g       ^ (row & 7)) * 8));
      bA[m][1] = *(const bf16x8*)(As + row * 64 + (((g + 4) ^ (row & 7)) * 8));
    }
    if (pf) stageB(t + 1);
    __builtin_amdgcn_s_barrier();
    asm volatile("s_waitcnt lgkmcnt(0)" ::: "memory");
    __builtin_amdgcn_sched_barrier(0);
    __builtin_amdgcn_s_setprio(1);
    #pragma unroll
    for (int m = 0; m < 2; ++m)
      #pragma unroll
      for (int n = 0; n < 2; ++n) {
        acc[m + 2][n] = mfma16(bA[m][0], bB[n][0], acc[m + 2][n]);
        acc[m + 2][n] = mfma16(bA[m][1], bB[n][1], acc[m + 2][n]);
      }
    __builtin_amdgcn_s_setprio(0);
    __builtin_amdgcn_s_barrier();

    // ---- phase 3: no reads/stage; MFMA m23 x n23 (all operands held)
    __builtin_amdgcn_s_setprio(1);
    #pragma unroll
    for (int m = 0; m < 2; ++m)
      #pragma unroll
      for (int n = 2; n < 4; ++n) {
        acc[m + 2][n] = mfma16(bA[m][0], bB[n][0], acc[m + 2][n]);
        acc[m + 2][n] = mfma16(bA[m][1], bB[n][1], acc[m + 2][n]);
      }
    __builtin_amdgcn_s_setprio(0);

    // ---- tile boundary: drain t+1's loads (issued 1-3 phases ago, near-cold), flip
    if (pf) {
      asm volatile("s_waitcnt vmcnt(0)" ::: "memory");
      __builtin_amdgcn_s_barrier();
    }
  }

  __syncthreads();   // LDS reused for epilogue
  {
    bf16_t* L = (bf16_t*)shmem;               // [256][136]
    #pragma unroll
    for (int m = 0; m < 4; ++m)
      #pragma unroll
      for (int n = 0; n < 4; ++n)
        #pragma unroll
        for (int i = 0; i < 4; ++i)
          L[(wm + m * 16 + 4 * g + i) * 136 + wn + n * 16 + c] = (bf16_t)acc[m][n][i];
    __syncthreads();
    #pragma unroll
    for (int p = 0; p < 8; ++p) {
      int idx = p * 4096 + tid * 8;
      int row = idx >> 7, col = idx & 127;
      bf16x8 v = *(const bf16x8*)(L + row * 136 + col);
      *(bf16x8*)(C + (m0 + row) * (size_t)N + n0 + col) = v;
    }
  }
}

// ---------------- GEMM: C[M][N] = A[M][K] * Bt[N][K]^T  (m97 structure, out-proj) ----------------
template<bool OUT_BF16>
__global__ __launch_bounds__(256, 2) void k_gemm(const bf16_t* __restrict__ A,
                                                 const bf16_t* __restrict__ Bt,
                                                 void* __restrict__ Cout,
                                                 const float* __restrict__ bias,
                                                 int M, int N, int K) {
  __shared__ __align__(16) uint8_t shmem[34816];
  bf16_t* As = (bf16_t*)shmem;
  bf16_t* Bs = As + 128 * 64;
  int id  = blockIdx.x;
  int seq = id >> 3;
  int nbg = seq >> 6, inner = seq & 63;           // 64-block group: 8 mb x 8 nb
  int mb = ((id & 7) << 3) + (inner >> 3);
  int nb = (nbg << 3) + (inner & 7);

  const int tid = threadIdx.x;
  const int lane = tid & 63, wv = tid >> 6;
  const int c = lane & 15, g = lane >> 4;
  const size_t m0 = (size_t)mb * 128, n0 = (size_t)nb * 128;
  const int wm = (wv >> 1) * 64, wn = (wv & 1) * 64;

  f32x4 zero = {0.f, 0.f, 0.f, 0.f};
  f32x4 acc[4][4];
  #pragma unroll
  for (int m = 0; m < 4; ++m)
    #pragma unroll
    for (int n = 0; n < 4; ++n) acc[m][n] = zero;

  for (int kt = 0; kt < K; kt += 64) {
    if (kt) __syncthreads();
    #pragma unroll
    for (int p = 0; p < 4; ++p) {
      int seg = p * 256 + tid;
      int r = seg >> 3, s = seg & 7;
      int sc = (s ^ (r & 7)) * 8;
      gload_lds16(A + (m0 + r) * (size_t)K + kt + sc, As + seg * 8);
    }
    #pragma unroll
    for (int p = 0; p < 4; ++p) {
      int seg = p * 256 + tid;
      int r = seg >> 3, s = seg & 7;
      int sc = (s ^ (r & 7)) * 8;
      gload_lds16(Bt + (n0 + r) * (size_t)K + kt + sc, Bs + seg * 8);
    }
    __syncthreads();
    #pragma unroll
    for (int kk = 0; kk < 2; ++kk) {
      bf16x8 af[4], bfv[4];
      #pragma unroll
      for (int m = 0; m < 4; ++m) {
        int row = wm + m * 16 + c;
        int sl = (g + 4 * kk) ^ (row & 7);
        af[m] = *(const bf16x8*)(As + row * 64 + sl * 8);
      }
      #pragma unroll
      for (int n = 0; n < 4; ++n) {
        int row = wn + n * 16 + c;
        int sl = (g + 4 * kk) ^ (row & 7);
        bfv[n] = *(const bf16x8*)(Bs + row * 64 + sl * 8);
      }
      #pragma unroll
      for (int m = 0; m < 4; ++m)
        #pragma unroll
        for (int n = 0; n < 4; ++n)
          acc[m][n] = mfma16(af[m], bfv[n], acc[m][n]);
    }
  }

  __syncthreads();
  if (OUT_BF16) {
    bf16_t* L = (bf16_t*)shmem;               // [128][136]
    #pragma unroll
    for (int m = 0; m < 4; ++m)
      #pragma unroll
      for (int n = 0; n < 4; ++n)
        #pragma unroll
        for (int i = 0; i < 4; ++i)
          L[(wm + m * 16 + 4 * g + i) * 136 + wn + n * 16 + c] = (bf16_t)acc[m][n][i];
    __syncthreads();
    bf16_t* C = (bf16_t*)Cout;
    #pragma unroll
    for (int p = 0; p < 8; ++p) {
      int idx = p * 2048 + tid * 8;
      int row = idx >> 7, col = idx & 127;
      bf16x8 v = *(const bf16x8*)(L + row * 136 + col);
      *(bf16x8*)(C + (m0 + row) * (size_t)N + n0 + col) = v;
    }
  } else {
    float* C = (float*)Cout;
    float* L = (float*)shmem;                 // [64][132]
    #pragma unroll
    for (int half = 0; half < 2; ++half) {
      if (half) __syncthreads();
      if ((wv >> 1) == half) {
        #pragma unroll
        for (int m = 0; m < 4; ++m)
          #pragma unroll
          for (int n = 0; n < 4; ++n)
            #pragma unroll
            for (int i = 0; i < 4; ++i)
              L[(m * 16 + 4 * g + i) * 132 + wn + n * 16 + c] = acc[m][n][i];
      }
      __syncthreads();
      #pragma unroll
      for (int p = 0; p < 8; ++p) {
        int lin = p * 1024 + tid * 4;
        int row = lin >> 7, col = lin & 127;
        float4 v = *(const float4*)(L + row * 132 + col);
        float4 bv = *(const float4*)(bias + n0 + col);
        v.x += bv.x; v.y += bv.y; v.z += bv.z; v.w += bv.w;
        *(float4*)(C + (m0 + half * 64 + row) * (size_t)N + n0 + col) = v;
      }
    }
  }
}

// ---------------- fused attention: local attn (bid<512) + ctx partials via MFMA (bid>=512) ----
__global__ __launch_bounds__(512) void k_attn(const bf16_t* __restrict__ qkv,
                                              const uint8_t* __restrict__ valid,
                                              bf16_t* __restrict__ attn,
                                              float* __restrict__ ctxp,
                                              float* __restrict__ sump) {
  __shared__ __align__(16) uint8_t smem[50688];
  int bid = blockIdx.x;
  int tid = threadIdx.x;
  const int lane = tid & 63, wv = tid >> 6;
  const int c = lane & 15, g = lane >> 4;
  f32x4 zero = {0.f, 0.f, 0.f, 0.f};

  if (bid < 512) {
    bf16_t* Ks = (bf16_t*)smem;               // [384][64] swizzled   (phase 1)
    bf16_t* VT = (bf16_t*)smem;               // [64][392] transposed (phase 3, aliases Ks)
    uint8_t* s_key = smem + 50176;            // [384]
    uint8_t* s_q   = smem + 50560;            // [128]

    int w = bid & 31, h = (bid >> 5) & 7, b = bid >> 8;
    const int tkbase = (w - 1) * 128;

    // ---- phase 0: stage K (swizzled) + masks
    #pragma unroll
    for (int p = 0; p < 6; ++p) {
      int seg = p * 512 + tid;
      int r = seg >> 3, s = seg & 7;
      int tk = tkbase + r;
      bf16x8 v8 = { (bf16_t)0.f,(bf16_t)0.f,(bf16_t)0.f,(bf16_t)0.f,
                    (bf16_t)0.f,(bf16_t)0.f,(bf16_t)0.f,(bf16_t)0.f };
      if ((unsigned)tk < 4096u)
        v8 = *(const bf16x8*)(qkv + (size_t)(b * 4096 + tk) * 3072 + 1024 + h * 64 + s * 8);
      *(bf16x8*)(Ks + r * 64 + ((s ^ (r & 7)) * 8)) = v8;
    }
    if (tid < 384) {
      int tk = tkbase + tid;
      s_key[tid] = ((unsigned)tk < 4096u) ? valid[b * 4096 + tk] : (uint8_t)0;
    }
    if (tid < 128) s_q[tid] = valid[b * 4096 + w * 128 + tid];
    __syncthreads();

    // ---- phase 1: S^T = K Q^T
    int m0 = wv * 16;
    bf16x8 qa0, qa1;
    {
      const bf16_t* qrow = qkv + (size_t)(b * 4096 + w * 128 + m0 + c) * 3072 + h * 64;
      qa0 = *(const bf16x8*)(qrow + g * 8);
      qa1 = *(const bf16x8*)(qrow + 32 + g * 8);
    }
    f32x4 acc[24];
    #pragma unroll
    for (int nt = 0; nt < 24; ++nt) acc[nt] = zero;
    #pragma unroll
    for (int nt = 0; nt < 24; ++nt) {
      int n = nt * 16 + c;
      bf16x8 k0 = *(const bf16x8*)(Ks + n * 64 + ((g       ^ (n & 7)) * 8));
      bf16x8 k1 = *(const bf16x8*)(Ks + n * 64 + (((g + 4) ^ (n & 7)) * 8));
      acc[nt] = mfma16(k0, qa0, acc[nt]);
      acc[nt] = mfma16(k1, qa1, acc[nt]);
    }
    __syncthreads();   // all waves done reading Ks -> region reusable

    // ---- phase 2a: stage V^T (vector global loads + scalar LDS writes)
    #pragma unroll
    for (int p = 0; p < 6; ++p) {
      int seg = p * 512 + tid;
      int r = seg >> 3, s = seg & 7;
      int tk = tkbase + r;
      bf16x8 v8 = { (bf16_t)0.f,(bf16_t)0.f,(bf16_t)0.f,(bf16_t)0.f,
                    (bf16_t)0.f,(bf16_t)0.f,(bf16_t)0.f,(bf16_t)0.f };
      if ((unsigned)tk < 4096u)
        v8 = *(const bf16x8*)(qkv + (size_t)(b * 4096 + tk) * 3072 + 2048 + h * 64 + s * 8);
      #pragma unroll
      for (int j = 0; j < 8; ++j)
        VT[(s * 8 + j) * 392 + r] = v8[j];
    }

    // ---- phase 2b: mask + softmax + pack + lane-exchange
    bool qv = s_q[m0 + c] != 0;
    #pragma unroll
    for (int nt = 0; nt < 24; ++nt) {
      u32 kv4 = *(const u32*)(s_key + nt * 16 + 4 * g);
      #pragma unroll
      for (int i = 0; i < 4; ++i) {
        bool kv = ((kv4 >> (8 * i)) & 255u) != 0u;
        acc[nt][i] = (qv && kv) ? acc[nt][i] * 0.125f : NEGF;
      }
    }
    float mx = NEGF;
    #pragma unroll
    for (int nt = 0; nt < 24; ++nt)
      #pragma unroll
      for (int i = 0; i < 4; ++i) mx = fmaxf(mx, acc[nt][i]);
    mx = fmaxf(mx, __shfl_xor(mx, 16, 64));
    mx = fmaxf(mx, __shfl_xor(mx, 32, 64));

    const int srcA = ((lane >> 4) & 1) * 32 + (lane & 15);
    const int srcB = srcA + 16;
    union Pk2 { bf16x4 h; uint2 u; };
    union Pk4 { uint4 u; bf16x8 h; };
    uint4 paU[12];
    #pragma unroll
    for (int ks = 0; ks < 12; ++ks) paU[ks] = make_uint4(0, 0, 0, 0);
    float sum = 0.f;
    #pragma unroll
    for (int nt = 0; nt < 24; ++nt) {
      Pk2 pk;
      #pragma unroll
      for (int i = 0; i < 4; ++i) {
        float e = __expf(acc[nt][i] - mx);
        sum += e;
        pk.h[i] = (bf16_t)e;
      }
      u32 a0 = (u32)__shfl((int)pk.u.x, srcA, 64);
      u32 a1 = (u32)__shfl((int)pk.u.y, srcA, 64);
      u32 b0 = (u32)__shfl((int)pk.u.x, srcB, 64);
      u32 b1 = (u32)__shfl((int)pk.u.y, srcB, 64);
      bool take = ((g >> 1) == (nt & 1));
      int ks = nt >> 1;
      paU[ks].x = take ? a0 : paU[ks].x;
      paU[ks].y = take ? a1 : paU[ks].y;
      paU[ks].z = take ? b0 : paU[ks].z;
      paU[ks].w = take ? b1 : paU[ks].w;
    }
    sum += __shfl_xor(sum, 16, 64);
    sum += __shfl_xor(sum, 32, 64);
    float inv = 1.f / sum;
    float invq[4];
    #pragma unroll
    for (int i = 0; i < 4; ++i) invq[i] = __shfl(inv, 4 * g + i, 64);
    __syncthreads();   // VT writes complete everywhere

    // ---- phase 3: O = P V, scale by invq at store
    f32x4 o[4];
    #pragma unroll
    for (int n = 0; n < 4; ++n) o[n] = zero;
    #pragma unroll
    for (int ks = 0; ks < 12; ++ks) {
      Pk4 pa; pa.u = paU[ks];
      #pragma unroll
      for (int n = 0; n < 4; ++n) {
        bf16x8 vb = *(const bf16x8*)(VT + (n * 16 + c) * 392 + ks * 32 + g * 8);
        o[n] = mfma16(pa.h, vb, o[n]);
      }
    }
    size_t obase = (size_t)(b * 4096 + w * 128 + m0) * 1024 + h * 64;
    #pragma unroll
    for (int n = 0; n < 4; ++n)
      #pragma unroll
      for (int i = 0; i < 4; ++i)
        attn[obase + (size_t)(4 * g + i) * 1024 + n * 16 + c] = (bf16_t)(o[n][i] * invq[i]);
  } else {
    // ======== linear-attn context partials via MFMA ========
    int bid2 = bid - 512;
    int tc = bid2 & 15, h = (bid2 >> 4) & 7, b = bid2 >> 7;
    bf16_t* eKT = (bf16_t*)smem;              // [64][136]
    bf16_t* vT  = (bf16_t*)(smem + 17408);    // [64][136]
    int dt = wv >> 1, et2 = (wv & 1) * 2;
    f32x4 acc2[2];
    acc2[0] = zero; acc2[1] = zero;
    float rowsum = 0.f;
    int rsrow = wv * 8 + (lane >> 3);
    int rscol = (lane & 7) * 16;
    for (int ch = 0; ch < 2; ++ch) {
      __syncthreads();
      #pragma unroll
      for (int p = 0; p < 2; ++p) {
        int idx = p * 512 + tid;
        int r = idx >> 3, ss = idx & 7;
        int gt = b * 4096 + tc * 256 + ch * 128 + r;
        bool vld = valid[gt] != 0;
        bf16x8 k8 = *(const bf16x8*)(qkv + (size_t)gt * 3072 + 1024 + (8 + h) * 64 + ss * 8);
        bf16x8 v8 = *(const bf16x8*)(qkv + (size_t)gt * 3072 + 2048 + (8 + h) * 64 + ss * 8);
        #pragma unroll
        for (int j = 0; j < 8; ++j) {
          int dd = ss * 8 + j;
          eKT[dd * 136 + r] = vld ? (bf16_t)__expf((float)k8[j]) : (bf16_t)0.f;
          vT [dd * 136 + r] = vld ? v8[j] : (bf16_t)0.f;
        }
      }
      __syncthreads();
      #pragma unroll
      for (int ks = 0; ks < 4; ++ks) {
        bf16x8 af = *(const bf16x8*)(eKT + (dt * 16 + c) * 136 + ks * 32 + g * 8);
        #pragma unroll
        for (int n = 0; n < 2; ++n) {
          bf16x8 bf = *(const bf16x8*)(vT + ((et2 + n) * 16 + c) * 136 + ks * 32 + g * 8);
          acc2[n] = mfma16(af, bf, acc2[n]);
        }
      }
      float s = 0.f;
      #pragma unroll
      for (int q = 0; q < 2; ++q) {
        bf16x8 e8 = *(const bf16x8*)(eKT + rsrow * 136 + rscol + q * 8);
        #pragma unroll
        for (int j = 0; j < 8; ++j) s += (float)e8[j];
      }
      rowsum += s;
    }
    rowsum += __shfl_xor(rowsum, 1, 64);
    rowsum += __shfl_xor(rowsum, 2, 64);
    rowsum += __shfl_xor(rowsum, 4, 64);
    size_t slice = (size_t)((b * 8 + h) * 16 + tc);
    #pragma unroll
    for (int n = 0; n < 2; ++n)
      #pragma unroll
      for (int i = 0; i < 4; ++i)
        ctxp[slice * 4096 + (size_t)(dt * 16 + 4 * g + i) * 64 + (et2 + n) * 16 + c] = acc2[n][i];
    if ((lane & 7) == 0)
      sump[slice * 64 + rsrow] = rowsum;
  }
}

// ---------------- combine partials, normalize, write transposed bf16 ----------------
__global__ __launch_bounds__(256) void k_ctx2(const float* __restrict__ ctxp,
                                              const float* __restrict__ sump,
                                              bf16_t* __restrict__ ctxT) {
  int bh = blockIdx.x;   // 16
  int tid = threadIdx.x;
  __shared__ float inv[64];
  if (tid < 64) {
    float s = 0.f;
    #pragma unroll
    for (int tc = 0; tc < 16; ++tc)
      s += sump[(size_t)(bh * 16 + tc) * 64 + tid];
    inv[tid] = 1.f / s;
  }
  __syncthreads();
  for (int p = 0; p < 16; ++p) {
    int lin = p * 256 + tid;
    int d = lin >> 6, e = lin & 63;
    float s = 0.f;
    #pragma unroll
    for (int tc = 0; tc < 16; ++tc)
      s += ctxp[(size_t)(bh * 16 + tc) * 4096 + lin];
    s *= inv[d];
    ctxT[(size_t)bh * 4096 + e * 64 + d] = (bf16_t)s;   // transposed: [e][d]
  }
}

// ---------------- linear out: attn = softmax(q)*0.125 @ ctx ----------------
__global__ __launch_bounds__(256) void k_linout(const bf16_t* __restrict__ qkv,
                                                const bf16_t* __restrict__ ctxT,
                                                bf16_t* __restrict__ attn) {
  int bid = blockIdx.x;
  int tb2 = bid & 15, hg = (bid >> 4) & 7, b = bid >> 7;
  int tid = threadIdx.x;
  __shared__ bf16_t qs[256 * 72];
  __shared__ bf16_t cT[64 * 72];
  {
    int t = tb2 * 256 + tid;
    const bf16_t* qrow = qkv + (size_t)(b * 4096 + t) * 3072 + (8 + hg) * 64;
    float x[64];
    #pragma unroll
    for (int s8 = 0; s8 < 8; ++s8) {
      bf16x8 q8 = *(const bf16x8*)(qrow + s8 * 8);
      #pragma unroll
      for (int j = 0; j < 8; ++j) x[s8 * 8 + j] = (float)q8[j];
    }
    float m = x[0];
    #pragma unroll
    for (int i = 1; i < 64; ++i) m = fmaxf(m, x[i]);
    float sum = 0.f;
    #pragma unroll
    for (int i = 0; i < 64; ++i) { x[i] = __expf(x[i] - m); sum += x[i]; }
    float sc = 0.125f / sum;
    #pragma unroll
    for (int s8 = 0; s8 < 8; ++s8) {
      bf16x8 o8;
      #pragma unroll
      for (int j = 0; j < 8; ++j) o8[j] = (bf16_t)(x[s8 * 8 + j] * sc);
      *(bf16x8*)(qs + tid * 72 + s8 * 8) = o8;
    }
  }
  for (int idx = tid; idx < 512; idx += 256) {
    int r = idx >> 3, s = idx & 7;
    *(bf16x8*)(cT + r * 72 + s * 8) =
      *(const bf16x8*)(ctxT + (size_t)(b * 8 + hg) * 4096 + r * 64 + s * 8);
  }
  __syncthreads();
  int lane = tid & 63, wvv = tid >> 6;
  int c = lane & 15, g = lane >> 4;
  int m0w = wvv * 64;
  f32x4 zero = {0.f, 0.f, 0.f, 0.f};
  f32x4 acc[4][4];
  #pragma unroll
  for (int m = 0; m < 4; ++m)
    #pragma unroll
    for (int n = 0; n < 4; ++n) acc[m][n] = zero;
  #pragma unroll
  for (int kk = 0; kk < 2; ++kk) {
    bf16x8 af[4], bfv[4];
    #pragma unroll
    for (int m = 0; m < 4; ++m)
      af[m] = *(const bf16x8*)(qs + (m0w + m * 16 + c) * 72 + kk * 32 + g * 8);
    #pragma unroll
    for (int n = 0; n < 4; ++n)
      bfv[n] = *(const bf16x8*)(cT + (n * 16 + c) * 72 + kk * 32 + g * 8);
    #pragma unroll
    for (int m = 0; m < 4; ++m)
      #pragma unroll
      for (int n = 0; n < 4; ++n)
        acc[m][n] = mfma16(af[m], bfv[n], acc[m][n]);
  }
  size_t obase = (size_t)(b * 4096 + tb2 * 256 + m0w) * 1024 + (8 + hg) * 64;
  #pragma unroll
  for (int m = 0; m < 4; ++m)
    #pragma unroll
    for (int n = 0; n < 4; ++n)
      #pragma unroll
      for (int i = 0; i < 4; ++i)
        attn[obase + (size_t)(m * 16 + 4 * g + i) * 1024 + n * 16 + c] = (bf16_t)acc[m][n][i];
}

// ---------------- launcher ----------------
extern "C" void kernel_launch(void* const* d_in, const int* in_sizes, int n_in,
                              void* d_out, int out_size, void* d_ws, size_t ws_size,
                              hipStream_t stream) {
  const float*   x    = (const float*)d_in[0];
  const uint8_t* mraw = (const uint8_t*)d_in[1];
  const float*   Wq   = (const float*)d_in[2];
  const float*   Wk   = (const float*)d_in[3];
  const float*   Wv   = (const float*)d_in[4];
  const float*   Wo   = (const float*)d_in[5];
  const float*   bo   = (const float*)d_in[6];
  uint8_t* ws = (uint8_t*)d_ws;

  uint8_t* valid = ws;                                   //      8192 B
  bf16_t*  xb    = (bf16_t*)(ws + 8192);                 //  16777216 B
  bf16_t*  WT    = (bf16_t*)(ws + 16785408);             //   6291456 B
  bf16_t*  WoT   = (bf16_t*)(ws + 23076864);             //   2097152 B
  bf16_t*  qkv   = (bf16_t*)(ws + 25174016);             //  50331648 B
  bf16_t*  attn  = (bf16_t*)(ws + 75505664);             //  16777216 B
  // ctx scratch aliases xb (dead after the QKV GEMM; rewritten every replay)
  float*   ctxp  = (float*)(ws + 8192);                  //   4194304 B
  float*   sump  = (float*)(ws + 4202496);               //     65536 B
  bf16_t*  ctxT  = (bf16_t*)(ws + 4268032);              //    131072 B

  k_prep_all<<<12289, 256, 0, stream>>>(x, mraw, Wq, Wk, Wv, Wo, xb, WT, WoT, valid);
  k_gemm8p<<<768, 512, 0, stream>>>(xb, WT, qkv, 8192, 3072, 1024);
  k_attn<<<768, 512, 0, stream>>>(qkv, valid, attn, ctxp, sump);
  k_ctx2<<<16, 256, 0, stream>>>(ctxp, sump, ctxT);
  k_linout<<<256, 256, 0, stream>>>(qkv, ctxT, attn);
  k_gemm<false><<<512, 256, 0, stream>>>(attn, WoT, d_out, bo, 8192, 1024, 1024);
}

// Round 15
// 176.002 us; speedup vs baseline: 1.0706x; 1.0706x over previous
//
#include <hip/hip_runtime.h>
#include <cstdint>
#include <cfloat>
#include <math.h>

typedef __bf16 bf16_t;
typedef __bf16 bf16x8 __attribute__((ext_vector_type(8)));
typedef __bf16 bf16x4 __attribute__((ext_vector_type(4)));
typedef float  f32x4  __attribute__((ext_vector_type(4)));
typedef unsigned int u32;

#define NEGF (-3.4028234663852886e38f)

static __device__ __forceinline__ f32x4 mfma16(bf16x8 a, bf16x8 b, f32x4 c) {
  return __builtin_amdgcn_mfma_f32_16x16x32_bf16(a, b, c, 0, 0, 0);
}
static __device__ __forceinline__ void gload_lds16(const bf16_t* g, bf16_t* l) {
  __builtin_amdgcn_global_load_lds((const __attribute__((address_space(1))) void*)g,
                                   (__attribute__((address_space(3))) void*)l, 16, 0, 0);
}

// ---------------- fused prep: mask decode + x cast + weight transpose ----------------
__global__ __launch_bounds__(256) void k_prep_all(const float* __restrict__ x,
                                                  const uint8_t* __restrict__ mraw,
                                                  const float* __restrict__ Wq,
                                                  const float* __restrict__ Wk,
                                                  const float* __restrict__ Wv,
                                                  const float* __restrict__ Wo,
                                                  bf16_t* __restrict__ xb,
                                                  bf16_t* __restrict__ WT,
                                                  bf16_t* __restrict__ WoT,
                                                  uint8_t* __restrict__ valid) {
  int bid = blockIdx.x;
  int tid = threadIdx.x;
  if (bid < 8192) {                      // cast x -> bf16
    int i = bid * 256 + tid;
    float4 v = ((const float4*)x)[i];
    bf16x4 o = { (bf16_t)v.x, (bf16_t)v.y, (bf16_t)v.z, (bf16_t)v.w };
    *(bf16x4*)(xb + (size_t)i * 4) = o;
  } else if (bid < 12288) {              // transpose+cast weights
    __shared__ float tile[32][33];
    int zz = bid - 8192;
    int z = zz >> 10, rem = zz & 1023;
    int bx = rem & 31, by = rem >> 5;
    const float* src = (z == 0) ? Wq : (z == 1) ? Wk : (z == 2) ? Wv : Wo;
    bf16_t* dst = (z < 3) ? (WT + (size_t)z * 1024 * 1024) : WoT;
    int x0 = bx * 32, y0 = by * 32;
    int tx = tid & 31, ty = tid >> 5;
    #pragma unroll
    for (int j = 0; j < 32; j += 8)
      tile[ty + j][tx] = src[(size_t)(y0 + ty + j) * 1024 + x0 + tx];
    __syncthreads();
    #pragma unroll
    for (int j = 0; j < 32; j += 8)
      dst[(size_t)(x0 + ty + j) * 1024 + y0 + tx] = (bf16_t)tile[tx][ty + j];
  } else {                               // mask decode (layout auto-detect)
    __shared__ int f1, f3;
    if (tid == 0) { f1 = 0; f3 = 0; }
    __syncthreads();
    int l1 = 0, l3 = 0;
    for (int i = tid; i < 8192; i += 256) {
      uint8_t v = mraw[i];
      if (v) { int r = i & 3; if (r == 1 || r == 2) l1 = 1; if (r == 3) l3 = 1; }
    }
    if (l1) atomicOr(&f1, 1);
    if (l3) atomicOr(&f3, 1);
    __syncthreads();
    int layout = f1 ? 0 : (f3 ? 2 : 1);
    for (int i = tid; i < 8192; i += 256) {
      bool m;
      if (layout == 0)      m = mraw[i] != 0;
      else if (layout == 1) m = ((const int*)mraw)[i] != 0;
      else                  m = ((const float*)mraw)[i] != 0.0f;
      valid[i] = m ? (uint8_t)0 : (uint8_t)1;
    }
  }
}

// ---------------- GEMM: C[M][N] = A[M][K] * Bt[N][K]^T  (m97 structure) ----------------
// LDS epilogue (contiguous 256B stores). Block order: per-XCD groups of 8 mb x 8 nb.
// Three 8-phase/pipelined variants (R3, R8, R14) all regressed to ~1 block/CU,
// MfmaUtil 28-31%; this 2-block/CU structure at 39% is the session's ceiling.
template<bool OUT_BF16>
__global__ __launch_bounds__(256, 2) void k_gemm(const bf16_t* __restrict__ A,
                                                 const bf16_t* __restrict__ Bt,
                                                 void* __restrict__ Cout,
                                                 const float* __restrict__ bias,
                                                 int M, int N, int K) {
  __shared__ __align__(16) uint8_t shmem[34816];
  bf16_t* As = (bf16_t*)shmem;
  bf16_t* Bs = As + 128 * 64;
  int id  = blockIdx.x;
  int seq = id >> 3;
  int nbg = seq >> 6, inner = seq & 63;           // 64-block group: 8 mb x 8 nb
  int mb = ((id & 7) << 3) + (inner >> 3);        // XCD-bijective, L2-grouped
  int nb = (nbg << 3) + (inner & 7);

  const int tid = threadIdx.x;
  const int lane = tid & 63, wv = tid >> 6;
  const int c = lane & 15, g = lane >> 4;
  const size_t m0 = (size_t)mb * 128, n0 = (size_t)nb * 128;
  const int wm = (wv >> 1) * 64, wn = (wv & 1) * 64;

  f32x4 zero = {0.f, 0.f, 0.f, 0.f};
  f32x4 acc[4][4];
  #pragma unroll
  for (int m = 0; m < 4; ++m)
    #pragma unroll
    for (int n = 0; n < 4; ++n) acc[m][n] = zero;

  for (int kt = 0; kt < K; kt += 64) {
    if (kt) __syncthreads();
    #pragma unroll
    for (int p = 0; p < 4; ++p) {
      int seg = p * 256 + tid;
      int r = seg >> 3, s = seg & 7;
      int sc = (s ^ (r & 7)) * 8;
      gload_lds16(A + (m0 + r) * (size_t)K + kt + sc, As + seg * 8);
    }
    #pragma unroll
    for (int p = 0; p < 4; ++p) {
      int seg = p * 256 + tid;
      int r = seg >> 3, s = seg & 7;
      int sc = (s ^ (r & 7)) * 8;
      gload_lds16(Bt + (n0 + r) * (size_t)K + kt + sc, Bs + seg * 8);
    }
    __syncthreads();
    #pragma unroll
    for (int kk = 0; kk < 2; ++kk) {
      bf16x8 af[4], bfv[4];
      #pragma unroll
      for (int m = 0; m < 4; ++m) {
        int row = wm + m * 16 + c;
        int sl = (g + 4 * kk) ^ (row & 7);
        af[m] = *(const bf16x8*)(As + row * 64 + sl * 8);
      }
      #pragma unroll
      for (int n = 0; n < 4; ++n) {
        int row = wn + n * 16 + c;
        int sl = (g + 4 * kk) ^ (row & 7);
        bfv[n] = *(const bf16x8*)(Bs + row * 64 + sl * 8);
      }
      #pragma unroll
      for (int m = 0; m < 4; ++m)
        #pragma unroll
        for (int n = 0; n < 4; ++n)
          acc[m][n] = mfma16(af[m], bfv[n], acc[m][n]);
    }
  }

  __syncthreads();
  if (OUT_BF16) {
    bf16_t* L = (bf16_t*)shmem;               // [128][136]
    #pragma unroll
    for (int m = 0; m < 4; ++m)
      #pragma unroll
      for (int n = 0; n < 4; ++n)
        #pragma unroll
        for (int i = 0; i < 4; ++i)
          L[(wm + m * 16 + 4 * g + i) * 136 + wn + n * 16 + c] = (bf16_t)acc[m][n][i];
    __syncthreads();
    bf16_t* C = (bf16_t*)Cout;
    #pragma unroll
    for (int p = 0; p < 8; ++p) {
      int idx = p * 2048 + tid * 8;
      int row = idx >> 7, col = idx & 127;
      bf16x8 v = *(const bf16x8*)(L + row * 136 + col);
      *(bf16x8*)(C + (m0 + row) * (size_t)N + n0 + col) = v;
    }
  } else {
    float* C = (float*)Cout;
    float* L = (float*)shmem;                 // [64][132]
    #pragma unroll
    for (int half = 0; half < 2; ++half) {
      if (half) __syncthreads();
      if ((wv >> 1) == half) {
        #pragma unroll
        for (int m = 0; m < 4; ++m)
          #pragma unroll
          for (int n = 0; n < 4; ++n)
            #pragma unroll
            for (int i = 0; i < 4; ++i)
              L[(m * 16 + 4 * g + i) * 132 + wn + n * 16 + c] = acc[m][n][i];
      }
      __syncthreads();
      #pragma unroll
      for (int p = 0; p < 8; ++p) {
        int lin = p * 1024 + tid * 4;
        int row = lin >> 7, col = lin & 127;
        float4 v = *(const float4*)(L + row * 132 + col);
        float4 bv = *(const float4*)(bias + n0 + col);
        v.x += bv.x; v.y += bv.y; v.z += bv.z; v.w += bv.w;
        *(float4*)(C + (m0 + half * 64 + row) * (size_t)N + n0 + col) = v;
      }
    }
  }
}

// ---------------- fused attention: local attn (bid<512) + ctx partials via MFMA (bid>=512) ----
__global__ __launch_bounds__(512) void k_attn(const bf16_t* __restrict__ qkv,
                                              const uint8_t* __restrict__ valid,
                                              bf16_t* __restrict__ attn,
                                              float* __restrict__ ctxp,
                                              float* __restrict__ sump) {
  __shared__ __align__(16) uint8_t smem[50688];
  int bid = blockIdx.x;
  int tid = threadIdx.x;
  const int lane = tid & 63, wv = tid >> 6;
  const int c = lane & 15, g = lane >> 4;
  f32x4 zero = {0.f, 0.f, 0.f, 0.f};

  if (bid < 512) {
    // ======== local attention: swapped QK^T, in-register P ========
    bf16_t* Ks = (bf16_t*)smem;               // [384][64] swizzled   (phase 1)
    bf16_t* VT = (bf16_t*)smem;               // [64][392] transposed (phase 3, aliases Ks)
    uint8_t* s_key = smem + 50176;            // [384]
    uint8_t* s_q   = smem + 50560;            // [128]

    int w = bid & 31, h = (bid >> 5) & 7, b = bid >> 8;
    const int tkbase = (w - 1) * 128;

    // ---- phase 0: stage K (swizzled) + masks
    #pragma unroll
    for (int p = 0; p < 6; ++p) {
      int seg = p * 512 + tid;
      int r = seg >> 3, s = seg & 7;
      int tk = tkbase + r;
      bf16x8 v8 = { (bf16_t)0.f,(bf16_t)0.f,(bf16_t)0.f,(bf16_t)0.f,
                    (bf16_t)0.f,(bf16_t)0.f,(bf16_t)0.f,(bf16_t)0.f };
      if ((unsigned)tk < 4096u)
        v8 = *(const bf16x8*)(qkv + (size_t)(b * 4096 + tk) * 3072 + 1024 + h * 64 + s * 8);
      *(bf16x8*)(Ks + r * 64 + ((s ^ (r & 7)) * 8)) = v8;
    }
    if (tid < 384) {
      int tk = tkbase + tid;
      s_key[tid] = ((unsigned)tk < 4096u) ? valid[b * 4096 + tk] : (uint8_t)0;
    }
    if (tid < 128) s_q[tid] = valid[b * 4096 + w * 128 + tid];
    __syncthreads();

    // ---- phase 1: S^T = K Q^T
    int m0 = wv * 16;
    bf16x8 qa0, qa1;
    {
      const bf16_t* qrow = qkv + (size_t)(b * 4096 + w * 128 + m0 + c) * 3072 + h * 64;
      qa0 = *(const bf16x8*)(qrow + g * 8);
      qa1 = *(const bf16x8*)(qrow + 32 + g * 8);
    }
    f32x4 acc[24];
    #pragma unroll
    for (int nt = 0; nt < 24; ++nt) acc[nt] = zero;
    #pragma unroll
    for (int nt = 0; nt < 24; ++nt) {
      int n = nt * 16 + c;
      bf16x8 k0 = *(const bf16x8*)(Ks + n * 64 + ((g       ^ (n & 7)) * 8));
      bf16x8 k1 = *(const bf16x8*)(Ks + n * 64 + (((g + 4) ^ (n & 7)) * 8));
      acc[nt] = mfma16(k0, qa0, acc[nt]);
      acc[nt] = mfma16(k1, qa1, acc[nt]);
    }
    __syncthreads();   // all waves done reading Ks -> region reusable

    // ---- phase 2a: stage V^T (vector global loads + scalar LDS writes)
    #pragma unroll
    for (int p = 0; p < 6; ++p) {
      int seg = p * 512 + tid;
      int r = seg >> 3, s = seg & 7;
      int tk = tkbase + r;
      bf16x8 v8 = { (bf16_t)0.f,(bf16_t)0.f,(bf16_t)0.f,(bf16_t)0.f,
                    (bf16_t)0.f,(bf16_t)0.f,(bf16_t)0.f,(bf16_t)0.f };
      if ((unsigned)tk < 4096u)
        v8 = *(const bf16x8*)(qkv + (size_t)(b * 4096 + tk) * 3072 + 2048 + h * 64 + s * 8);
      #pragma unroll
      for (int j = 0; j < 8; ++j)
        VT[(s * 8 + j) * 392 + r] = v8[j];
    }

    // ---- phase 2b: mask + softmax + pack + lane-exchange
    bool qv = s_q[m0 + c] != 0;
    #pragma unroll
    for (int nt = 0; nt < 24; ++nt) {
      u32 kv4 = *(const u32*)(s_key + nt * 16 + 4 * g);
      #pragma unroll
      for (int i = 0; i < 4; ++i) {
        bool kv = ((kv4 >> (8 * i)) & 255u) != 0u;
        acc[nt][i] = (qv && kv) ? acc[nt][i] * 0.125f : NEGF;
      }
    }
    float mx = NEGF;
    #pragma unroll
    for (int nt = 0; nt < 24; ++nt)
      #pragma unroll
      for (int i = 0; i < 4; ++i) mx = fmaxf(mx, acc[nt][i]);
    mx = fmaxf(mx, __shfl_xor(mx, 16, 64));
    mx = fmaxf(mx, __shfl_xor(mx, 32, 64));

    const int srcA = ((lane >> 4) & 1) * 32 + (lane & 15);
    const int srcB = srcA + 16;
    union Pk2 { bf16x4 h; uint2 u; };
    union Pk4 { uint4 u; bf16x8 h; };
    uint4 paU[12];
    #pragma unroll
    for (int ks = 0; ks < 12; ++ks) paU[ks] = make_uint4(0, 0, 0, 0);
    float sum = 0.f;
    #pragma unroll
    for (int nt = 0; nt < 24; ++nt) {
      Pk2 pk;
      #pragma unroll
      for (int i = 0; i < 4; ++i) {
        float e = __expf(acc[nt][i] - mx);
        sum += e;
        pk.h[i] = (bf16_t)e;
      }
      u32 a0 = (u32)__shfl((int)pk.u.x, srcA, 64);
      u32 a1 = (u32)__shfl((int)pk.u.y, srcA, 64);
      u32 b0 = (u32)__shfl((int)pk.u.x, srcB, 64);
      u32 b1 = (u32)__shfl((int)pk.u.y, srcB, 64);
      bool take = ((g >> 1) == (nt & 1));
      int ks = nt >> 1;
      paU[ks].x = take ? a0 : paU[ks].x;
      paU[ks].y = take ? a1 : paU[ks].y;
      paU[ks].z = take ? b0 : paU[ks].z;
      paU[ks].w = take ? b1 : paU[ks].w;
    }
    sum += __shfl_xor(sum, 16, 64);
    sum += __shfl_xor(sum, 32, 64);
    float inv = 1.f / sum;
    float invq[4];
    #pragma unroll
    for (int i = 0; i < 4; ++i) invq[i] = __shfl(inv, 4 * g + i, 64);
    __syncthreads();   // VT writes complete everywhere

    // ---- phase 3: O = P V, scale by invq at store
    f32x4 o[4];
    #pragma unroll
    for (int n = 0; n < 4; ++n) o[n] = zero;
    #pragma unroll
    for (int ks = 0; ks < 12; ++ks) {
      Pk4 pa; pa.u = paU[ks];
      #pragma unroll
      for (int n = 0; n < 4; ++n) {
        bf16x8 vb = *(const bf16x8*)(VT + (n * 16 + c) * 392 + ks * 32 + g * 8);
        o[n] = mfma16(pa.h, vb, o[n]);
      }
    }
    size_t obase = (size_t)(b * 4096 + w * 128 + m0) * 1024 + h * 64;
    #pragma unroll
    for (int n = 0; n < 4; ++n)
      #pragma unroll
      for (int i = 0; i < 4; ++i)
        attn[obase + (size_t)(4 * g + i) * 1024 + n * 16 + c] = (bf16_t)(o[n][i] * invq[i]);
  } else {
    // ======== linear-attn context partials via MFMA ========
    int bid2 = bid - 512;
    int tc = bid2 & 15, h = (bid2 >> 4) & 7, b = bid2 >> 7;
    bf16_t* eKT = (bf16_t*)smem;              // [64][136]
    bf16_t* vT  = (bf16_t*)(smem + 17408);    // [64][136]
    int dt = wv >> 1, et2 = (wv & 1) * 2;
    f32x4 acc2[2];
    acc2[0] = zero; acc2[1] = zero;
    float rowsum = 0.f;
    int rsrow = wv * 8 + (lane >> 3);
    int rscol = (lane & 7) * 16;
    for (int ch = 0; ch < 2; ++ch) {
      __syncthreads();
      #pragma unroll
      for (int p = 0; p < 2; ++p) {
        int idx = p * 512 + tid;
        int r = idx >> 3, ss = idx & 7;
        int gt = b * 4096 + tc * 256 + ch * 128 + r;
        bool vld = valid[gt] != 0;
        bf16x8 k8 = *(const bf16x8*)(qkv + (size_t)gt * 3072 + 1024 + (8 + h) * 64 + ss * 8);
        bf16x8 v8 = *(const bf16x8*)(qkv + (size_t)gt * 3072 + 2048 + (8 + h) * 64 + ss * 8);
        #pragma unroll
        for (int j = 0; j < 8; ++j) {
          int dd = ss * 8 + j;
          eKT[dd * 136 + r] = vld ? (bf16_t)__expf((float)k8[j]) : (bf16_t)0.f;
          vT [dd * 136 + r] = vld ? v8[j] : (bf16_t)0.f;
        }
      }
      __syncthreads();
      #pragma unroll
      for (int ks = 0; ks < 4; ++ks) {
        bf16x8 af = *(const bf16x8*)(eKT + (dt * 16 + c) * 136 + ks * 32 + g * 8);
        #pragma unroll
        for (int n = 0; n < 2; ++n) {
          bf16x8 bf = *(const bf16x8*)(vT + ((et2 + n) * 16 + c) * 136 + ks * 32 + g * 8);
          acc2[n] = mfma16(af, bf, acc2[n]);
        }
      }
      float s = 0.f;
      #pragma unroll
      for (int q = 0; q < 2; ++q) {
        bf16x8 e8 = *(const bf16x8*)(eKT + rsrow * 136 + rscol + q * 8);
        #pragma unroll
        for (int j = 0; j < 8; ++j) s += (float)e8[j];
      }
      rowsum += s;
    }
    rowsum += __shfl_xor(rowsum, 1, 64);
    rowsum += __shfl_xor(rowsum, 2, 64);
    rowsum += __shfl_xor(rowsum, 4, 64);
    size_t slice = (size_t)((b * 8 + h) * 16 + tc);
    #pragma unroll
    for (int n = 0; n < 2; ++n)
      #pragma unroll
      for (int i = 0; i < 4; ++i)
        ctxp[slice * 4096 + (size_t)(dt * 16 + 4 * g + i) * 64 + (et2 + n) * 16 + c] = acc2[n][i];
    if ((lane & 7) == 0)
      sump[slice * 64 + rsrow] = rowsum;
  }
}

// ---------------- combine partials, normalize, write transposed bf16 ----------------
__global__ __launch_bounds__(256) void k_ctx2(const float* __restrict__ ctxp,
                                              const float* __restrict__ sump,
                                              bf16_t* __restrict__ ctxT) {
  int bh = blockIdx.x;   // 16
  int tid = threadIdx.x;
  __shared__ float inv[64];
  if (tid < 64) {
    float s = 0.f;
    #pragma unroll
    for (int tc = 0; tc < 16; ++tc)
      s += sump[(size_t)(bh * 16 + tc) * 64 + tid];
    inv[tid] = 1.f / s;
  }
  __syncthreads();
  for (int p = 0; p < 16; ++p) {
    int lin = p * 256 + tid;
    int d = lin >> 6, e = lin & 63;
    float s = 0.f;
    #pragma unroll
    for (int tc = 0; tc < 16; ++tc)
      s += ctxp[(size_t)(bh * 16 + tc) * 4096 + lin];
    s *= inv[d];
    ctxT[(size_t)bh * 4096 + e * 64 + d] = (bf16_t)s;   // transposed: [e][d]
  }
}

// ---------------- linear out: attn = softmax(q)*0.125 @ ctx ----------------
__global__ __launch_bounds__(256) void k_linout(const bf16_t* __restrict__ qkv,
                                                const bf16_t* __restrict__ ctxT,
                                                bf16_t* __restrict__ attn) {
  int bid = blockIdx.x;
  int tb2 = bid & 15, hg = (bid >> 4) & 7, b = bid >> 7;
  int tid = threadIdx.x;
  __shared__ bf16_t qs[256 * 72];
  __shared__ bf16_t cT[64 * 72];
  {
    int t = tb2 * 256 + tid;
    const bf16_t* qrow = qkv + (size_t)(b * 4096 + t) * 3072 + (8 + hg) * 64;
    float x[64];
    #pragma unroll
    for (int s8 = 0; s8 < 8; ++s8) {
      bf16x8 q8 = *(const bf16x8*)(qrow + s8 * 8);
      #pragma unroll
      for (int j = 0; j < 8; ++j) x[s8 * 8 + j] = (float)q8[j];
    }
    float m = x[0];
    #pragma unroll
    for (int i = 1; i < 64; ++i) m = fmaxf(m, x[i]);
    float sum = 0.f;
    #pragma unroll
    for (int i = 0; i < 64; ++i) { x[i] = __expf(x[i] - m); sum += x[i]; }
    float sc = 0.125f / sum;
    #pragma unroll
    for (int s8 = 0; s8 < 8; ++s8) {
      bf16x8 o8;
      #pragma unroll
      for (int j = 0; j < 8; ++j) o8[j] = (bf16_t)(x[s8 * 8 + j] * sc);
      *(bf16x8*)(qs + tid * 72 + s8 * 8) = o8;
    }
  }
  for (int idx = tid; idx < 512; idx += 256) {
    int r = idx >> 3, s = idx & 7;
    *(bf16x8*)(cT + r * 72 + s * 8) =
      *(const bf16x8*)(ctxT + (size_t)(b * 8 + hg) * 4096 + r * 64 + s * 8);
  }
  __syncthreads();
  int lane = tid & 63, wvv = tid >> 6;
  int c = lane & 15, g = lane >> 4;
  int m0w = wvv * 64;
  f32x4 zero = {0.f, 0.f, 0.f, 0.f};
  f32x4 acc[4][4];
  #pragma unroll
  for (int m = 0; m < 4; ++m)
    #pragma unroll
    for (int n = 0; n < 4; ++n) acc[m][n] = zero;
  #pragma unroll
  for (int kk = 0; kk < 2; ++kk) {
    bf16x8 af[4], bfv[4];
    #pragma unroll
    for (int m = 0; m < 4; ++m)
      af[m] = *(const bf16x8*)(qs + (m0w + m * 16 + c) * 72 + kk * 32 + g * 8);
    #pragma unroll
    for (int n = 0; n < 4; ++n)
      bfv[n] = *(const bf16x8*)(cT + (n * 16 + c) * 72 + kk * 32 + g * 8);
    #pragma unroll
    for (int m = 0; m < 4; ++m)
      #pragma unroll
      for (int n = 0; n < 4; ++n)
        acc[m][n] = mfma16(af[m], bfv[n], acc[m][n]);
  }
  size_t obase = (size_t)(b * 4096 + tb2 * 256 + m0w) * 1024 + (8 + hg) * 64;
  #pragma unroll
  for (int m = 0; m < 4; ++m)
    #pragma unroll
    for (int n = 0; n < 4; ++n)
      #pragma unroll
      for (int i = 0; i < 4; ++i)
        attn[obase + (size_t)(m * 16 + 4 * g + i) * 1024 + n * 16 + c] = (bf16_t)acc[m][n][i];
}

// ---------------- launcher ----------------
extern "C" void kernel_launch(void* const* d_in, const int* in_sizes, int n_in,
                              void* d_out, int out_size, void* d_ws, size_t ws_size,
                              hipStream_t stream) {
  const float*   x    = (const float*)d_in[0];
  const uint8_t* mraw = (const uint8_t*)d_in[1];
  const float*   Wq   = (const float*)d_in[2];
  const float*   Wk   = (const float*)d_in[3];
  const float*   Wv   = (const float*)d_in[4];
  const float*   Wo   = (const float*)d_in[5];
  const float*   bo   = (const float*)d_in[6];
  uint8_t* ws = (uint8_t*)d_ws;

  uint8_t* valid = ws;                                   //      8192 B
  bf16_t*  xb    = (bf16_t*)(ws + 8192);                 //  16777216 B
  bf16_t*  WT    = (bf16_t*)(ws + 16785408);             //   6291456 B
  bf16_t*  WoT   = (bf16_t*)(ws + 23076864);             //   2097152 B
  bf16_t*  qkv   = (bf16_t*)(ws + 25174016);             //  50331648 B
  bf16_t*  attn  = (bf16_t*)(ws + 75505664);             //  16777216 B
  // ctx scratch aliases xb (dead after the QKV GEMM; rewritten every replay)
  float*   ctxp  = (float*)(ws + 8192);                  //   4194304 B
  float*   sump  = (float*)(ws + 4202496);               //     65536 B
  bf16_t*  ctxT  = (bf16_t*)(ws + 4268032);              //    131072 B

  k_prep_all<<<12289, 256, 0, stream>>>(x, mraw, Wq, Wk, Wv, Wo, xb, WT, WoT, valid);
  k_gemm<true><<<1536, 256, 0, stream>>>(xb, WT, (void*)qkv, nullptr, 8192, 3072, 1024);
  k_attn<<<768, 512, 0, stream>>>(qkv, valid, attn, ctxp, sump);
  k_ctx2<<<16, 256, 0, stream>>>(ctxp, sump, ctxT);
  k_linout<<<256, 256, 0, stream>>>(qkv, ctxT, attn);
  k_gemm<false><<<512, 256, 0, stream>>>(attn, WoT, d_out, bo, 8192, 1024, 1024);
}